// Round 1
// baseline (203.857 us; speedup 1.0000x reference)
//
#include <hip/hip_runtime.h>
#include <stdint.h>

// InstanceHead on MI355X — f32/int32 inputs, f32 OUTPUT buffer.
// N=100000, M=256, B=8, L=128, D=64.
// R8: occupancy release.  R7 kept dv[16][4] = 64 live f32/lane -> unified
// VGPR+AGPR footprint ~140 -> 3 waves/SIMD (measured Occupancy 32%),
// latency-bound (VALUBusy 36%, MFMA 2.5%, HBM 21%).  R8 removes the stored
// attention array entirely:
//   pass1: d^2 only (no sqrt/exp) -> d2min
//   pass2: recompute d^2, sqrt+exp -> rsum
//   pass3: recompute e bit-identically inside the GEMM2 epilogue
// Batch validity is folded into geometry: x += 4096*batch (exact in f32;
// in-batch diffs cancel exactly, cross-batch d>=3073 -> exp underflows to
// exact 0).  No block barrier (clu_s slice is wave-private; DS pipe is
// in-order per wave).  Target <= ~80 unified regs -> whole grid resident.

#define NN 100000
#define MM 256
#define LL 128
#define DD 64
#define NTILES (NN / 16)  // 6250, exact

typedef float f32x4 __attribute__((ext_vector_type(4)));
typedef __bf16 bf16x8 __attribute__((ext_vector_type(8)));

union U16x8 { uint4 u; bf16x8 v; unsigned short s[8]; };

static __device__ __forceinline__ unsigned short f2bf(float f) {
  union { float f; unsigned int i; } t; t.f = f;
  unsigned int x = t.i;
  x += 0x7fffu + ((x >> 16) & 1u);  // round-to-nearest-even
  return (unsigned short)(x >> 16);
}

// ---------------- prep: cen (bf16), W^T (bf16), centroid meta ----------------
__global__ __launch_bounds__(256) void prep_kernel(
    const int* __restrict__ cen_coords,
    const float* __restrict__ cen_feats,
    const float* __restrict__ conf,
    const float* __restrict__ W,
    const float* __restrict__ bvec,
    unsigned short* __restrict__ cen_ws,   // [256][64] bf16
    unsigned short* __restrict__ wt_ws,    // [64][128] bf16 (W transposed)
    float4* __restrict__ cmeta_ws)         // [256] {x+4096*batch, y, z, 0}
{
  int tid = threadIdx.x;
  if (blockIdx.x < 16) {
    int m = blockIdx.x * 16 + (tid >> 4);
    int c = tid & 15;
    float a0 = 0.f, a1 = 0.f, a2 = 0.f, a3 = 0.f;
    for (int l = 0; l < LL; l++) {
      float f = cen_feats[m * LL + l];
      const float* wr = W + l * DD + c;
      a0 += f * wr[0];  a1 += f * wr[16];
      a2 += f * wr[32]; a3 += f * wr[48];
    }
    float cf = conf[m];
    cen_ws[m * DD + c +  0] = f2bf(cf * (a0 + bvec[c +  0]));
    cen_ws[m * DD + c + 16] = f2bf(cf * (a1 + bvec[c + 16]));
    cen_ws[m * DD + c + 32] = f2bf(cf * (a2 + bvec[c + 32]));
    cen_ws[m * DD + c + 48] = f2bf(cf * (a3 + bvec[c + 48]));
  } else {
    for (int i = tid; i < LL * DD; i += 256) {
      int l = i >> 6, d = i & 63;
      wt_ws[d * LL + l] = f2bf(W[l * DD + d]);
    }
    {
      int4 cc = ((const int4*)cen_coords)[tid];  // {batch, x, y, z}
      float4 f;
      f.x = (float)cc.y + 4096.0f * (float)cc.x;  // batch folded into x
      f.y = (float)cc.z;
      f.z = (float)cc.w;
      f.w = 0.0f;
      cmeta_ws[tid] = f;
    }
  }
}

// ---------------- main: 1 wave per 16-row tile, no barrier ----------------
__global__ __launch_bounds__(256) void main_kernel(
    const int4* __restrict__ clu_coords4,
    const float* __restrict__ feats,
    const float* __restrict__ bvec,
    const unsigned short* __restrict__ cen_ws,
    const unsigned short* __restrict__ wt_ws,
    const float4* __restrict__ cmeta,
    float* __restrict__ out)
{
  __shared__ __align__(16) unsigned short clu_s[4][16 * 72];  // wave-private slices

  int tid = threadIdx.x;
  int wave = tid >> 6, lane = tid & 63;
  int q = lane >> 4, c = lane & 15;
  int tile = blockIdx.x * 4 + wave;
  if (tile >= NTILES) return;  // wave-autonomous: dead waves exit now

  // ---- GEMM1: clu = feats @ W (+b).  A from global f32 feats (cvt->bf16),
  //      B from ws bf16 W^T (cache-resident).
  f32x4 acc[4] = {{0,0,0,0},{0,0,0,0},{0,0,0,0},{0,0,0,0}};
  {
    const float4* fb = (const float4*)(feats + (size_t)(tile * 16 + c) * LL);
    const uint4* wb = (const uint4*)wt_ws;
#pragma unroll
    for (int ks = 0; ks < 4; ks++) {
      float4 f0 = fb[ks * 8 + q * 2];
      float4 f1 = fb[ks * 8 + q * 2 + 1];
      U16x8 a;
      a.s[0] = f2bf(f0.x); a.s[1] = f2bf(f0.y); a.s[2] = f2bf(f0.z); a.s[3] = f2bf(f0.w);
      a.s[4] = f2bf(f1.x); a.s[5] = f2bf(f1.y); a.s[6] = f2bf(f1.z); a.s[7] = f2bf(f1.w);
#pragma unroll
      for (int nt = 0; nt < 4; nt++) {
        U16x8 b; b.u = wb[(nt * 16 + c) * 16 + ks * 4 + q];
        acc[nt] = __builtin_amdgcn_mfma_f32_16x16x32_bf16(a.v, b.v, acc[nt], 0, 0, 0);
      }
    }
  }
#pragma unroll
  for (int nt = 0; nt < 4; nt++) {
    float bv = bvec[nt * 16 + c];
    acc[nt][0] += bv; acc[nt][1] += bv; acc[nt][2] += bv; acc[nt][3] += bv;
  }
  // ---- row L2 norms (row r = q*4+reg lives across the 16 lanes of quad q)
  float inv_nrm[4];
#pragma unroll
  for (int r = 0; r < 4; r++) {
    float s = acc[0][r]*acc[0][r] + acc[1][r]*acc[1][r] + acc[2][r]*acc[2][r] + acc[3][r]*acc[3][r];
    s += __shfl_xor(s, 1); s += __shfl_xor(s, 2); s += __shfl_xor(s, 4); s += __shfl_xor(s, 8);
    inv_nrm[r] = 1.0f / fmaxf(sqrtf(s), 1e-12f);
  }
  // ---- clu tile -> LDS (bf16); norm folded into epilogue scale
#pragma unroll
  for (int nt = 0; nt < 4; nt++)
#pragma unroll
    for (int r = 0; r < 4; r++)
      clu_s[wave][(q * 4 + r) * 72 + nt * 16 + c] = f2bf(acc[nt][r]);

  // Wave-private LDS transpose: DS pipe is in-order per wave, so the reads
  // below see the writes without a block barrier.  Pin compiler ordering.
  __builtin_amdgcn_sched_barrier(0);

  // ---- GEMM2 A-frags from LDS
  const uint4* cb = (const uint4*)(clu_s[wave]);
  U16x8 a0, a1;
  a0.u = cb[c * 9 + q];       // k = 0..31
  a1.u = cb[c * 9 + 4 + q];   // k = 32..63

  // ---- row meta for this lane's 4 C-rows (batch folded into x, exact)
  float rx[4], ry[4], rz[4];
#pragma unroll
  for (int r = 0; r < 4; r++) {
    int4 rm = clu_coords4[tile * 16 + q * 4 + r];
    rx[r] = (float)rm.y + 4096.0f * (float)rm.x;
    ry[r] = (float)rm.z;
    rz[r] = (float)rm.w;
  }

  // ---- pass 1: d^2 min only (no sqrt, no exp, no stored array)
  float d2m[4] = {1e30f, 1e30f, 1e30f, 1e30f};
#pragma unroll
  for (int mt = 0; mt < 16; mt++) {
    float4 cm = cmeta[mt * 16 + c];
#pragma unroll
    for (int r = 0; r < 4; r++) {
      float dx = rx[r] - cm.x, dy = ry[r] - cm.y, dz = rz[r] - cm.z;
      float d2 = dx * dx + dy * dy + dz * dz;
      d2m[r] = fminf(d2m[r], d2);
    }
  }
  float dmv[4];
#pragma unroll
  for (int r = 0; r < 4; r++) {
    d2m[r] = fminf(d2m[r], __shfl_xor(d2m[r], 1));
    d2m[r] = fminf(d2m[r], __shfl_xor(d2m[r], 2));
    d2m[r] = fminf(d2m[r], __shfl_xor(d2m[r], 4));
    d2m[r] = fminf(d2m[r], __shfl_xor(d2m[r], 8));
    dmv[r] = fmaxf(sqrtf(d2m[r]), 0.1f);  // clamped min dist (softmax max)
  }

  // ---- pass 2: recompute d, e = exp(dmin - d); row sums
  float rsum[4] = {0.f, 0.f, 0.f, 0.f};
#pragma unroll
  for (int mt = 0; mt < 16; mt++) {
    float4 cm = cmeta[mt * 16 + c];
#pragma unroll
    for (int r = 0; r < 4; r++) {
      float dx = rx[r] - cm.x, dy = ry[r] - cm.y, dz = rz[r] - cm.z;
      float d = fmaxf(sqrtf(dx * dx + dy * dy + dz * dz), 0.1f);
      rsum[r] += __expf(dmv[r] - d);  // cross-batch: arg <= -1301 -> exact 0
    }
  }
  float scale[4];
#pragma unroll
  for (int r = 0; r < 4; r++) {
    rsum[r] += __shfl_xor(rsum[r], 1);
    rsum[r] += __shfl_xor(rsum[r], 2);
    rsum[r] += __shfl_xor(rsum[r], 4);
    rsum[r] += __shfl_xor(rsum[r], 8);
    // d2m > 4e6 <=> no same-batch centroid for this row -> exact-zero row
    scale[r] = (d2m[r] < 4.0e6f) ? inv_nrm[r] / rsum[r] : 0.f;
  }

  // ---- pass 3 (epilogue): GEMM2 per m-tile + bit-identical e recompute
  const uint4* cenb = (const uint4*)cen_ws;
  float* op[4];
#pragma unroll
  for (int r = 0; r < 4; r++)
    op[r] = out + (size_t)(tile * 16 + q * 4 + r) * MM + c;

#pragma unroll
  for (int mt = 0; mt < 16; mt++) {
    U16x8 b0, b1;
    b0.u = cenb[(mt * 16 + c) * 8 + q];
    b1.u = cenb[(mt * 16 + c) * 8 + 4 + q];
    f32x4 dacc = {0, 0, 0, 0};
    dacc = __builtin_amdgcn_mfma_f32_16x16x32_bf16(a0.v, b0.v, dacc, 0, 0, 0);
    dacc = __builtin_amdgcn_mfma_f32_16x16x32_bf16(a1.v, b1.v, dacc, 0, 0, 0);
    float4 cm = cmeta[mt * 16 + c];
#pragma unroll
    for (int r = 0; r < 4; r++) {
      float dx = rx[r] - cm.x, dy = ry[r] - cm.y, dz = rz[r] - cm.z;
      float d = fmaxf(sqrtf(dx * dx + dy * dy + dz * dz), 0.1f);
      float e = __expf(dmv[r] - d);      // same ops as pass 2 -> bit-identical
      op[r][mt * 16] = dacc[r] * (e * scale[r]);  // imm-offset stores (mt*64 B)
    }
  }
}

extern "C" void kernel_launch(void* const* d_in, const int* in_sizes, int n_in,
                              void* d_out, int out_size, void* d_ws, size_t ws_size,
                              hipStream_t stream) {
  const int* clu_coords = (const int*)d_in[0];
  const int* cen_coords = (const int*)d_in[1];
  const float* clu_feats = (const float*)d_in[2];
  const float* cen_feats = (const float*)d_in[3];
  const float* conf      = (const float*)d_in[4];
  const float* W         = (const float*)d_in[5];
  const float* bvec      = (const float*)d_in[6];
  float* out = (float*)d_out;

  char* ws = (char*)d_ws;
  unsigned short* cen_ws = (unsigned short*)ws;              // 32768 B
  unsigned short* wt_ws  = (unsigned short*)(ws + 32768);    // 16384 B
  float4* cmeta_ws       = (float4*)(ws + 32768 + 16384);    // 4096 B

  prep_kernel<<<17, 256, 0, stream>>>(cen_coords, cen_feats, conf, W, bvec,
                                      cen_ws, wt_ws, cmeta_ws);
  main_kernel<<<(NTILES + 3) / 4, 256, 0, stream>>>(
      (const int4*)clu_coords, clu_feats, bvec, cen_ws, wt_ws, cmeta_ws, out);
}